// Round 3
// baseline (294.014 us; speedup 1.0000x reference)
//
#include <hip/hip_runtime.h>
#include <math.h>

// Shapes (fixed by the reference)
#define BB   16
#define CC   16      // IN_CHAN
#define LL   4096
#define OUTC 64
#define KS   7

// LDS x-window: 64 output positions + generous halo for the deformable offsets
#define HALO 16
#define WIN  96          // staged positions per block
#define XST  17          // padded stride (floats) -> spreads banks, 17 coprime 32

typedef float vfloat4 __attribute__((ext_vector_type(4)));

__global__ __launch_bounds__(256) void deform_conv_kernel(
    const float* __restrict__ x,    // (B,1,L,C) -> x[(b*L + l)*C + c]
    const float* __restrict__ p_w,  // (7,1,3)
    const float* __restrict__ p_b,  // (7,)
    const float* __restrict__ m_w,  // (7,1,3)
    const float* __restrict__ m_b,  // (7,)
    const float* __restrict__ c_w,  // (64,1,7)
    const float* __restrict__ c_b,  // (64,)
    float* __restrict__ out)        // (B,64,L,C)
{
    __shared__ float cw_lds[OUTC * 8];   // [o][0..6]=w, [7]=bias
    __shared__ float pw_lds[KS * 4];     // [k][0..2]=taps, [3]=bias
    __shared__ float mw_lds[KS * 4];
    __shared__ float xs[WIN * XST];      // staged x window, [dpos][c] stride XST

    const int tid   = threadIdx.x;
    const int b     = blockIdx.x >> 6;   // 16 batches
    const int ltile = blockIdx.x & 63;   // 64 tiles of 64 positions
    const int base  = ltile * 64 - HALO; // window start position (may be <0)

    const float* xb = x + b * (LL * CC);

    // ---- stage weights ----
    for (int i = tid; i < OUTC * 8; i += 256) {
        int o = i >> 3, j = i & 7;
        cw_lds[i] = (j < 7) ? c_w[o * 7 + j] : c_b[o];
    }
    if (tid < KS * 4) {
        int k = tid >> 2, j = tid & 3;
        pw_lds[tid] = (j < 3) ? p_w[k * 3 + j] : p_b[k];
        mw_lds[tid] = (j < 3) ? m_w[k * 3 + j] : m_b[k];
    }
    // ---- stage x window (coalesced: consecutive tid -> consecutive floats) ----
    for (int i = tid; i < WIN * CC; i += 256) {
        int dpos = i >> 4;          // 0..95
        int c    = i & 15;
        int pos  = base + dpos;
        float v  = (pos >= 0 && pos < LL) ? xb[pos * CC + c] : 0.f;
        xs[dpos * XST + c] = v;
    }
    __syncthreads();

    const int cg = tid & 3;              // channel quad: c0 = cg*4
    const int lo = tid >> 2;             // 0..63 within tile
    const int l  = ltile * 64 + lo;
    const int c0 = cg * 4;
    const int dl = lo + HALO;            // this l's index in the window

    // 3-tap conv inputs from LDS (zero pad at signal boundaries)
    float s_m1[4], s_p1[4], s_0[4];
    #pragma unroll
    for (int c = 0; c < 4; ++c) {
        s_0[c]  = xs[dl * XST + c0 + c];
        s_m1[c] = (l > 0)      ? xs[(dl - 1) * XST + c0 + c] : 0.f;
        s_p1[c] = (l < LL - 1) ? xs[(dl + 1) * XST + c0 + c] : 0.f;
    }

    // Compute x_off[c][k] — bilinear gathers from the LDS window
    float xoff[4][KS];
    const float pl = (float)(l + 1);
    #pragma unroll
    for (int k = 0; k < KS; ++k) {
        float4 pw = *(const float4*)(pw_lds + k * 4);  // x,y,z = taps, w = bias
        float4 mw = *(const float4*)(mw_lds + k * 4);
        const float pn = (float)(k - 3);
        #pragma unroll
        for (int c = 0; c < 4; ++c) {
            float off  = pw.w + pw.x * s_m1[c] + pw.y * s_0[c] + pw.z * s_p1[c];
            float mact = mw.w + mw.x * s_m1[c] + mw.y * s_0[c] + mw.z * s_p1[c];
            float mm   = 1.f / (1.f + __expf(-mact));   // sigmoid

            float p    = pl + pn + off;
            float qltf = fminf(fmaxf(floorf(p), 0.f), (float)(LL - 1));
            float qrbf = fminf(qltf + 1.f, (float)(LL - 1));
            float pc   = fminf(fmaxf(p, 0.f), (float)(LL - 1));
            float glt  = 1.f + (qltf - pc);
            float grb  = 1.f - (qrbf - pc);

            int ilt = (int)qltf;
            int irb = (int)qrbf;
            int dlt = ilt - base;
            int drb = irb - base;
            int ci  = c0 + c;
            float xlt, xrb;
            if ((unsigned)dlt < WIN && (unsigned)drb < WIN) {
                xlt = xs[dlt * XST + ci];    // LDS gather (the ~always path)
                xrb = xs[drb * XST + ci];
            } else {
                xlt = xb[ilt * CC + ci];     // rare large-offset fallback
                xrb = xb[irb * CC + ci];
            }
            xoff[c][k] = (glt * xlt + grb * xrb) * mm;
        }
    }

    // 7 -> 64 output-channel dot; float4 nontemporal stores (write-streaming)
    float* outp = out + ((size_t)(b * OUTC) * LL + l) * CC + c0;
    #pragma unroll 4
    for (int o = 0; o < OUTC; ++o) {
        float4 w0 = *(const float4*)(cw_lds + o * 8);      // k=0..3
        float4 w1 = *(const float4*)(cw_lds + o * 8 + 4);  // k=4..6, bias
        float acc[4];
        #pragma unroll
        for (int c = 0; c < 4; ++c) {
            float a = w1.w;
            a += w0.x * xoff[c][0];
            a += w0.y * xoff[c][1];
            a += w0.z * xoff[c][2];
            a += w0.w * xoff[c][3];
            a += w1.x * xoff[c][4];
            a += w1.y * xoff[c][5];
            a += w1.z * xoff[c][6];
            acc[c] = a;
        }
        vfloat4 res;
        res.x = acc[0]; res.y = acc[1]; res.z = acc[2]; res.w = acc[3];
        __builtin_nontemporal_store(res, (vfloat4*)(outp + (size_t)o * (LL * CC)));
    }
}

extern "C" void kernel_launch(void* const* d_in, const int* in_sizes, int n_in,
                              void* d_out, int out_size, void* d_ws, size_t ws_size,
                              hipStream_t stream) {
    const float* x   = (const float*)d_in[0];
    const float* p_w = (const float*)d_in[1];
    const float* p_b = (const float*)d_in[2];
    const float* m_w = (const float*)d_in[3];
    const float* m_b = (const float*)d_in[4];
    const float* c_w = (const float*)d_in[5];
    const float* c_b = (const float*)d_in[6];
    float* out = (float*)d_out;

    // grid: 16 batches x 64 l-tiles; block: 256 threads = 64 l x 4 channel-quads
    deform_conv_kernel<<<dim3(BB * 64), dim3(256), 0, stream>>>(
        x, p_w, p_b, m_w, m_b, c_w, c_b, out);
}